// Round 9
// baseline (377.149 us; speedup 1.0000x reference)
//
#include <hip/hip_runtime.h>
#include <math.h>

#define NN 65536
#define EE 1048576
#define ET (EE + NN)

#define CAPB 5120          // staging capacity per coarse bucket (mean 4352, +11.6 sigma)
#define EPB 4096           // edges per pass-1 block
#define P1B (ET / EPB)     // 272 blocks

__device__ __forceinline__ float bflo(unsigned u) { return __uint_as_float(u << 16); }
__device__ __forceinline__ float bfhi(unsigned u) { return __uint_as_float(u & 0xffff0000u); }
__device__ __forceinline__ float bfw(unsigned u) { return __uint_as_float(u << 16); }
__device__ __forceinline__ float lrelu(float x) { return x > 0.f ? x : 0.2f * x; }
__device__ __forceinline__ unsigned short f2bf(float f) {
  unsigned u = __float_as_uint(f);
  return (unsigned short)((u + 0x7fffu + ((u >> 16) & 1u)) >> 16);
}

// ---------------- CSR build via 2-pass coarse-bucket counting sort ----------------
__global__ __launch_bounds__(256) void bucket_pass1(const int* __restrict__ ei,
                                                    unsigned* __restrict__ staging,
                                                    unsigned* __restrict__ staging2,
                                                    int* __restrict__ gcnt) {
  __shared__ int hist[256];
  __shared__ int lbase[256];
  int t = threadIdx.x;
  hist[t] = 0;
  __syncthreads();
  int base = blockIdx.x * EPB;
  unsigned pk[16];
  int bk[16];
  #pragma unroll
  for (int j = 0; j < 16; ++j) {
    int e = base + j * 256 + t;
    int s, d;
    if (e < EE) { s = ei[e]; d = ei[EE + e]; } else { s = d = e - EE; }
    pk[j] = ((unsigned)s << 8) | (unsigned)(d & 255);
    bk[j] = d >> 8;
    atomicAdd(&hist[bk[j]], 1);
  }
  __syncthreads();
  lbase[t] = atomicAdd(&gcnt[t], hist[t]);   // reserve contiguous chunk per bucket
  __syncthreads();
  #pragma unroll
  for (int j = 0; j < 16; ++j) {
    int e = base + j * 256 + t;
    int pos = atomicAdd(&lbase[bk[j]], 1);
    staging[(size_t)bk[j] * CAPB + pos] = pk[j];
    staging2[(size_t)bk[j] * CAPB + pos] = (unsigned)e;
  }
}

__global__ __launch_bounds__(256) void bucket_pass2(const unsigned* __restrict__ staging,
                                                    const unsigned* __restrict__ staging2,
                                                    const int* __restrict__ gcnt,
                                                    int* __restrict__ row_ptr,
                                                    unsigned short* __restrict__ col,
                                                    unsigned short* __restrict__ dste,
                                                    int* __restrict__ orig) {
  __shared__ int pref[256];
  __shared__ int hist[256];
  __shared__ int loc[256];
  __shared__ int cnt2[256];
  __shared__ unsigned lin[CAPB];
  __shared__ unsigned lout[CAPB];
  __shared__ int lorig[CAPB];
  int t = threadIdx.x, b = blockIdx.x;

  pref[t] = gcnt[t];
  hist[t] = 0;
  __syncthreads();
  for (int off = 1; off < 256; off <<= 1) {      // inclusive scan of bucket counts
    int v = (t >= off) ? pref[t - off] : 0;
    __syncthreads();
    pref[t] += v;
    __syncthreads();
  }
  int rowbase = (b > 0) ? pref[b - 1] : 0;
  int nb = gcnt[b];

  for (int i = t; i < nb; i += 256) {
    unsigned v = staging[(size_t)b * CAPB + i];
    lin[i] = v;
    atomicAdd(&hist[v & 255], 1);
  }
  __syncthreads();
  loc[t] = hist[t];
  __syncthreads();
  for (int off = 1; off < 256; off <<= 1) {      // inclusive scan of local hist
    int v = (t >= off) ? loc[t - off] : 0;
    __syncthreads();
    loc[t] += v;
    __syncthreads();
  }
  int excl = loc[t] - hist[t];
  row_ptr[b * 256 + t] = rowbase + excl;
  cnt2[t] = excl;
  if (b == 255 && t == 255) row_ptr[NN] = rowbase + nb;
  __syncthreads();
  for (int i = t; i < nb; i += 256) {
    unsigned v = lin[i];
    int r = atomicAdd(&cnt2[v & 255], 1);
    lout[r] = v;
    lorig[r] = (int)staging2[(size_t)b * CAPB + i];
  }
  __syncthreads();
  for (int i = t; i < nb; i += 256) {            // coalesced final writes
    unsigned v = lout[i];
    col[rowbase + i] = (unsigned short)(v >> 8);
    dste[rowbase + i] = (unsigned short)(b * 256 + (v & 255));
    orig[rowbase + i] = lorig[i];
  }
}

// -------- dense: h = x@W, al_s/al_d, residual; register-blocked over nodes --------
template<int DIN, int DOUT, int H, bool HAS_RES, int NPW>
__global__ __launch_bounds__(256) void gemm_al_kernel(
    const float* __restrict__ xin, const float* __restrict__ W,
    const float* __restrict__ asrc, const float* __restrict__ adst,
    const float* __restrict__ Aw, const float* __restrict__ Ab,
    unsigned short* __restrict__ hw16, float* __restrict__ res,
    float* __restrict__ als, float* __restrict__ ald,
    unsigned short* __restrict__ cs)
{
  constexpr int GPW = 64 / DOUT;
  constexpr int NPB = 4 * NPW * GPW;   // nodes per block (4 waves)
  constexpr int DINP = DIN + 4;        // padded LDS stride
  __shared__ float xs[NPB][DINP];

  int wave = threadIdx.x >> 6;
  int lane = threadIdx.x & 63;
  int l = lane % DOUT;
  int sub = lane / DOUT;
  int block_base = blockIdx.x * NPB;

  {
    constexpr int NV = NPB * DIN / 4;
    const float4* xin4 = (const float4*)(xin + (size_t)block_base * DIN);
    for (int i = threadIdx.x; i < NV; i += 256) {
      float4 v = xin4[i];
      int flat = i * 4;
      int nd = flat / DIN, k = flat % DIN;
      *(float4*)&xs[nd][k] = v;
    }
  }
  __syncthreads();

  int nl = wave * (NPW * GPW) + sub * NPW;
  float acc[NPW], racc[NPW];
  #pragma unroll
  for (int n = 0; n < NPW; ++n) { acc[n] = 0.f; racc[n] = 0.f; }

  for (int k = 0; k < DIN; k += 4) {
    float w0 = W[(k + 0) * DOUT + l];
    float w1 = W[(k + 1) * DOUT + l];
    float w2 = W[(k + 2) * DOUT + l];
    float w3 = W[(k + 3) * DOUT + l];
    float a0 = 0.f, a1 = 0.f, a2 = 0.f, a3 = 0.f;
    if (HAS_RES) {
      a0 = Aw[(k + 0) * DOUT + l];
      a1 = Aw[(k + 1) * DOUT + l];
      a2 = Aw[(k + 2) * DOUT + l];
      a3 = Aw[(k + 3) * DOUT + l];
    }
    #pragma unroll
    for (int n = 0; n < NPW; ++n) {
      float4 xv = *(const float4*)&xs[nl + n][k];
      acc[n] = fmaf(xv.x, w0, fmaf(xv.y, w1, fmaf(xv.z, w2, fmaf(xv.w, w3, acc[n]))));
      if (HAS_RES)
        racc[n] = fmaf(xv.x, a0, fmaf(xv.y, a1, fmaf(xv.z, a2, fmaf(xv.w, a3, racc[n]))));
    }
  }

  int head = l >> 2, c = l & 3;
  float sa = asrc[l];
  float da = adst[l];
  #pragma unroll
  for (int n = 0; n < NPW; ++n) {
    size_t node = (size_t)(block_base + nl + n);
    float hh = acc[n];
    hw16[node * DOUT + l] = f2bf(hh);
    if (HAS_RES) res[node * DOUT + l] = racc[n] + Ab[l];
    float ps = hh * sa, pd = hh * da;
    ps += __shfl_xor(ps, 1); ps += __shfl_xor(ps, 2);
    pd += __shfl_xor(pd, 1); pd += __shfl_xor(pd, 2);
    if (c == 0) {
      als[node * H + head] = ps;
      ald[node * H + head] = pd;
      cs[node * H + head] = f2bf(ps);
    }
  }
}

// ---------------- fused gather: bf16x2 channels, DOUT/2 lanes per node ----------------
template<int DOUT, int H, bool HAS_RES>
__global__ __launch_bounds__(256) void gat_gather_kernel(
    const int* __restrict__ row_ptr, const unsigned short* __restrict__ col,
    const float* __restrict__ als, const float* __restrict__ ald,
    const unsigned* __restrict__ hw2,   // bf16x2: channels (2l, 2l+1)
    const float* __restrict__ bias, const float* __restrict__ g,
    const float* __restrict__ be, const float* __restrict__ res,
    float* __restrict__ out, float* __restrict__ inv_s_out)
{
  constexpr int G = DOUT / 2;          // lanes per node
  int tid = blockIdx.x * 256 + threadIdx.x;
  int node = tid / G;
  int l = threadIdx.x % G;             // group lane: channels 2l, 2l+1
  int h = l >> 1;                      // head (2 lanes per head)

  int r0 = row_ptr[node], r1 = row_ptr[node + 1];
  float ald_h = ald[node * H + h];

  float acc0 = 0.f, acc1 = 0.f, ss = 0.f;
  int e = r0;
  for (; e + 3 < r1; e += 4) {
    int s0 = col[e], s1 = col[e + 1], s2 = col[e + 2], s3 = col[e + 3];
    float av0 = als[s0 * H + h];
    float av1 = als[s1 * H + h];
    float av2 = als[s2 * H + h];
    float av3 = als[s3 * H + h];
    unsigned p0 = hw2[s0 * G + l];
    unsigned p1 = hw2[s1 * G + l];
    unsigned p2 = hw2[s2 * G + l];
    unsigned p3 = hw2[s3 * G + l];
    float lg0 = lrelu(av0 + ald_h);
    float lg1 = lrelu(av1 + ald_h);
    float lg2 = lrelu(av2 + ald_h);
    float lg3 = lrelu(av3 + ald_h);
    float e0 = __expf(lg0), e1 = __expf(lg1), e2 = __expf(lg2), e3 = __expf(lg3);
    ss += (e0 + e1) + (e2 + e3);
    acc0 += e0 * bflo(p0) + e1 * bflo(p1) + e2 * bflo(p2) + e3 * bflo(p3);
    acc1 += e0 * bfhi(p0) + e1 * bfhi(p1) + e2 * bfhi(p2) + e3 * bfhi(p3);
  }
  for (; e < r1; ++e) {
    int s0 = col[e];
    float av0 = als[s0 * H + h];
    unsigned p0 = hw2[s0 * G + l];
    float lg0 = lrelu(av0 + ald_h);
    float e0 = __expf(lg0);
    ss += e0;
    acc0 += e0 * bflo(p0);
    acc1 += e0 * bfhi(p0);
  }

  float inv = 1.f / ss;                // identical across the 2 lanes of a head
  if ((l & 1) == 0) inv_s_out[node * H + h] = inv;

  // epilogue: normalize -> bias -> elu -> layernorm -> (+res), 2 channels/lane
  float2 bb = ((const float2*)bias)[l];
  float v0 = acc0 * inv + bb.x;
  float v1 = acc1 * inv + bb.y;
  v0 = v0 > 0.f ? v0 : expm1f(v0);
  v1 = v1 > 0.f ? v1 : expm1f(v1);
  float sum = v0 + v1;
  #pragma unroll
  for (int o = G / 2; o; o >>= 1) sum += __shfl_xor(sum, o);
  float mu = sum * (1.f / DOUT);
  float d0 = v0 - mu, d1 = v1 - mu;
  float vs = d0 * d0 + d1 * d1;
  #pragma unroll
  for (int o = G / 2; o; o >>= 1) vs += __shfl_xor(vs, o);
  float rstd = rsqrtf(vs * (1.f / DOUT) + 1e-5f);
  float2 gg = ((const float2*)g)[l];
  float2 ee = ((const float2*)be)[l];
  float y0 = d0 * rstd * gg.x + ee.x;
  float y1 = d1 * rstd * gg.y + ee.y;
  if (HAS_RES) {
    float2 rr = ((const float2*)res)[node * G + l];
    y0 += rr.x; y1 += rr.y;
  }
  ((float2*)out)[node * G + l] = make_float2(y0, y1);
}

// ---- all-layer amean in CSR order + bucket-stage by original edge id (pass 1) ----
// d-side rows are L1-hot (dst-sorted); s-side bf16 cs tables (3.5MB) are L2-resident.
__global__ __launch_bounds__(256) void amean_permute_pass1(
    const unsigned short* __restrict__ col, const unsigned short* __restrict__ dste,
    const int* __restrict__ orig,
    const unsigned* __restrict__ cs1, const unsigned* __restrict__ cs2,
    const unsigned* __restrict__ cs3,
    const float* __restrict__ ald1, const float* __restrict__ inv1,
    const float* __restrict__ ald2, const float* __restrict__ inv2,
    const float* __restrict__ ald3, const float* __restrict__ inv3,
    unsigned long long* __restrict__ pstag, int* __restrict__ gcnt2,
    float* __restrict__ ssum)
{
  __shared__ int hist[256];
  __shared__ int lbase[256];
  __shared__ float red[3][4];
  int t = threadIdx.x;
  hist[t] = 0;
  __syncthreads();
  int i = blockIdx.x * 256 + t;
  int oe = orig[i];
  bool valid = (oe < EE);
  int bk = oe >> 12;
  unsigned long long pk = 0;
  float ex1 = 0.f, ex2 = 0.f, ex3 = 0.f;
  if (valid) {
    int s = col[i], d = dste[i];
    // layer 1 (H=16)
    uint4 c0 = *(const uint4*)(cs1 + (size_t)s * 8);
    uint4 c1 = *(const uint4*)(cs1 + (size_t)s * 8 + 4);
    const float4* a4 = (const float4*)(ald1 + (size_t)d * 16);
    const float4* v4 = (const float4*)(inv1 + (size_t)d * 16);
    float t1 = 0.f;
    {
      unsigned C[8] = {c0.x, c0.y, c0.z, c0.w, c1.x, c1.y, c1.z, c1.w};
      #pragma unroll
      for (int q = 0; q < 4; ++q) {
        float4 a = a4[q], v = v4[q];
        float l0 = lrelu(bflo(C[2 * q]) + a.x);
        float l1 = lrelu(bfhi(C[2 * q]) + a.y);
        float l2 = lrelu(bflo(C[2 * q + 1]) + a.z);
        float l3 = lrelu(bfhi(C[2 * q + 1]) + a.w);
        t1 += __expf(l0) * v.x + __expf(l1) * v.y + __expf(l2) * v.z + __expf(l3) * v.w;
      }
    }
    t1 *= (1.f / 16.f);
    // layer 2 (H=8)
    uint4 c2 = *(const uint4*)(cs2 + (size_t)s * 4);
    const float4* b4 = (const float4*)(ald2 + (size_t)d * 8);
    const float4* w4 = (const float4*)(inv2 + (size_t)d * 8);
    float t2 = 0.f;
    {
      unsigned C[4] = {c2.x, c2.y, c2.z, c2.w};
      #pragma unroll
      for (int q = 0; q < 2; ++q) {
        float4 a = b4[q], v = w4[q];
        float l0 = lrelu(bflo(C[2 * q]) + a.x);
        float l1 = lrelu(bfhi(C[2 * q]) + a.y);
        float l2 = lrelu(bflo(C[2 * q + 1]) + a.z);
        float l3 = lrelu(bfhi(C[2 * q + 1]) + a.w);
        t2 += __expf(l0) * v.x + __expf(l1) * v.y + __expf(l2) * v.z + __expf(l3) * v.w;
      }
    }
    t2 *= (1.f / 8.f);
    // layer 3 (H=4)
    uint2 c3 = *(const uint2*)(cs3 + (size_t)s * 2);
    float4 a3 = *(const float4*)(ald3 + (size_t)d * 4);
    float4 v3 = *(const float4*)(inv3 + (size_t)d * 4);
    float l0 = lrelu(bflo(c3.x) + a3.x);
    float l1 = lrelu(bfhi(c3.x) + a3.y);
    float l2 = lrelu(bflo(c3.y) + a3.z);
    float l3 = lrelu(bfhi(c3.y) + a3.w);
    float t3 = (__expf(l0) * v3.x + __expf(l1) * v3.y +
                __expf(l2) * v3.z + __expf(l3) * v3.w) * (1.f / 4.f);

    ex1 = __expf(t1); ex2 = __expf(t2); ex3 = __expf(t3);
    pk = ((unsigned long long)(oe & 4095) << 48) |
         ((unsigned long long)f2bf(t3) << 32) |
         ((unsigned long long)f2bf(t2) << 16) |
         (unsigned long long)f2bf(t1);
    atomicAdd(&hist[bk], 1);
  }
  __syncthreads();
  lbase[t] = atomicAdd(&gcnt2[t], hist[t]);
  __syncthreads();
  if (valid) {
    int pos = atomicAdd(&lbase[bk], 1);
    pstag[(size_t)bk * 4096 + pos] = pk;
  }
  // global exp-sums
  #pragma unroll
  for (int o = 32; o; o >>= 1) {
    ex1 += __shfl_xor(ex1, o);
    ex2 += __shfl_xor(ex2, o);
    ex3 += __shfl_xor(ex3, o);
  }
  int w = t >> 6;
  if ((t & 63) == 0) { red[0][w] = ex1; red[1][w] = ex2; red[2][w] = ex3; }
  __syncthreads();
  if (t == 0) {
    atomicAdd(&ssum[0], (red[0][0] + red[0][1]) + (red[0][2] + red[0][3]));
    atomicAdd(&ssum[1], (red[1][0] + red[1][1]) + (red[1][2] + red[1][3]));
    atomicAdd(&ssum[2], (red[2][0] + red[2][1]) + (red[2][2] + red[2][3]));
  }
}

// ---- pass 2: unbucket via LDS, apply softmax scale, fully coalesced e-output writes ----
__global__ __launch_bounds__(256) void permute_pass2(
    const unsigned long long* __restrict__ pstag, const float* __restrict__ ssum,
    float* __restrict__ oute1, float* __restrict__ oute2, float* __restrict__ oute3)
{
  __shared__ float a1[4096], a2[4096], a3[4096];
  int t = threadIdx.x, b = blockIdx.x;
  float i1 = 1.f / ssum[0], i2 = 1.f / ssum[1], i3 = 1.f / ssum[2];
  for (int k = t; k < 4096; k += 256) {
    unsigned long long v = pstag[(size_t)b * 4096 + k];
    int idx = (int)(v >> 48);
    a1[idx] = __expf(bfw((unsigned)(v & 0xffffu))) * i1;
    a2[idx] = __expf(bfw((unsigned)((v >> 16) & 0xffffu))) * i2;
    a3[idx] = __expf(bfw((unsigned)((v >> 32) & 0xffffu))) * i3;
  }
  __syncthreads();
  size_t base = (size_t)b * 4096;
  for (int k = t; k < 4096; k += 256) {
    oute1[base + k] = a1[k];
    oute2[base + k] = a2[k];
    oute3[base + k] = a3[k];
  }
}

// ---------------- per-layer driver ----------------
template<int DIN, int DOUT, int H, bool HAS_RES>
static void run_layer(const float* xin, const float* W, const float* as_,
                      const float* ad_, const float* bias, const float* Aw,
                      const float* Ab, const float* g, const float* be,
                      const int* row_ptr, const unsigned short* col,
                      unsigned short* hw16, float* res, float* als, float* ald,
                      float* inv_s, unsigned short* cs,
                      float* hout, hipStream_t stream)
{
  constexpr int NPW = 8;
  constexpr int NPB = 4 * NPW * (64 / DOUT);
  constexpr int G = DOUT / 2;
  gemm_al_kernel<DIN, DOUT, H, HAS_RES, NPW><<<NN / NPB, 256, 0, stream>>>(
      xin, W, as_, ad_, Aw, Ab, hw16, res, als, ald, cs);
  gat_gather_kernel<DOUT, H, HAS_RES><<<(NN * G) / 256, 256, 0, stream>>>(
      row_ptr, col, als, ald, (const unsigned*)hw16, bias, g, be, res, hout, inv_s);
}

extern "C" void kernel_launch(void* const* d_in, const int* in_sizes, int n_in,
                              void* d_out, int out_size, void* d_ws, size_t ws_size,
                              hipStream_t stream)
{
  const float* x   = (const float*)d_in[0];
  const int*   ei  = (const int*)d_in[1];
  const float* W1  = (const float*)d_in[3];
  const float* as1 = (const float*)d_in[4];
  const float* ad1 = (const float*)d_in[5];
  const float* b1  = (const float*)d_in[6];
  const float* W2  = (const float*)d_in[7];
  const float* as2 = (const float*)d_in[8];
  const float* ad2 = (const float*)d_in[9];
  const float* b2  = (const float*)d_in[10];
  const float* W3  = (const float*)d_in[11];
  const float* as3 = (const float*)d_in[12];
  const float* ad3 = (const float*)d_in[13];
  const float* b3  = (const float*)d_in[14];
  const float* A1w = (const float*)d_in[15];
  const float* A1b = (const float*)d_in[16];
  const float* A2w = (const float*)d_in[17];
  const float* A2b = (const float*)d_in[18];
  const float* g1  = (const float*)d_in[19];
  const float* be1 = (const float*)d_in[20];
  const float* g2  = (const float*)d_in[21];
  const float* be2 = (const float*)d_in[22];
  const float* g3  = (const float*)d_in[23];
  const float* be3 = (const float*)d_in[24];

  float* ws = (float*)d_ws;
  size_t off = 0;
  float* h1       = ws + off; off += (size_t)NN * 64;
  float* h2       = ws + off; off += (size_t)NN * 32;
  unsigned short* hw16 = (unsigned short*)(ws + off); off += (size_t)NN * 32;
  float* res      = ws + off; off += (size_t)NN * 64;
  float* als      = ws + off; off += (size_t)NN * 16;
  float* ald1     = ws + off; off += (size_t)NN * 16;
  float* ald2     = ws + off; off += (size_t)NN * 8;
  float* ald3     = ws + off; off += (size_t)NN * 4;
  float* inv1     = ws + off; off += (size_t)NN * 16;
  float* inv2     = ws + off; off += (size_t)NN * 8;
  float* inv3     = ws + off; off += (size_t)NN * 4;
  unsigned short* cs1 = (unsigned short*)(ws + off); off += (size_t)NN * 8;
  unsigned short* cs2 = (unsigned short*)(ws + off); off += (size_t)NN * 4;
  unsigned short* cs3 = (unsigned short*)(ws + off); off += (size_t)NN * 2;
  float* scal     = ws + off; off += 16;
  int* row_ptr    = (int*)(ws + off); off += NN + 4;
  unsigned short* col  = (unsigned short*)(ws + off); off += ET / 2 + 4;
  unsigned short* dste = (unsigned short*)(ws + off); off += ET / 2 + 4;
  int* orig       = (int*)(ws + off); off += ET;
  int* gcnt       = (int*)(ws + off); off += 256;
  int* gcnt2      = (int*)(ws + off); off += 256;
  unsigned* staging  = (unsigned*)(ws + off); off += (size_t)256 * CAPB;
  unsigned* staging2 = (unsigned*)(ws + off); off += (size_t)256 * CAPB;
  if (off & 1) off++;  // 8B align
  unsigned long long* pstag = (unsigned long long*)(ws + off); off += (size_t)EE * 2;

  float* outh3 = (float*)d_out;
  float* oute1 = outh3 + (size_t)NN * 16;
  float* oute2 = oute1 + EE;
  float* oute3 = oute2 + EE;

  // ---- CSR build via coarse-bucket sort (graph-capture safe) ----
  hipMemsetAsync(gcnt, 0, 512 * sizeof(int), stream);   // gcnt + gcnt2 (adjacent)
  hipMemsetAsync(scal, 0, 16, stream);
  bucket_pass1<<<P1B, 256, 0, stream>>>(ei, staging, staging2, gcnt);
  bucket_pass2<<<256, 256, 0, stream>>>(staging, staging2, gcnt, row_ptr, col, dste, orig);

  run_layer<84, 64, 16, true>(x, W1, as1, ad1, b1, A1w, A1b, g1, be1,
                              row_ptr, col, hw16, res, als, ald1, inv1, cs1, h1, stream);
  run_layer<64, 32, 8, true>(h1, W2, as2, ad2, b2, A2w, A2b, g2, be2,
                             row_ptr, col, hw16, res, als, ald2, inv2, cs2, h2, stream);
  run_layer<32, 16, 4, false>(h2, W3, as3, ad3, b3, nullptr, nullptr, g3, be3,
                              row_ptr, col, hw16, res, als, ald3, inv3, cs3, outh3, stream);

  amean_permute_pass1<<<ET / 256, 256, 0, stream>>>(
      col, dste, orig, (const unsigned*)cs1, (const unsigned*)cs2, (const unsigned*)cs3,
      ald1, inv1, ald2, inv2, ald3, inv3, pstag, gcnt2, scal);
  permute_pass2<<<256, 256, 0, stream>>>(pstag, scal, oute1, oute2, oute3);
}

// Round 10
// 363.423 us; speedup vs baseline: 1.0378x; 1.0378x over previous
//
#include <hip/hip_runtime.h>
#include <math.h>

#define NN 65536
#define EE 1048576
#define ET (EE + NN)

#define CAPB 5120          // staging capacity per coarse bucket (mean 4352, +11.6 sigma)
#define EPB 4096           // edges per pass-1 block
#define P1B (ET / EPB)     // 272 blocks

__device__ __forceinline__ float bflo(unsigned u) { return __uint_as_float(u << 16); }
__device__ __forceinline__ float bfhi(unsigned u) { return __uint_as_float(u & 0xffff0000u); }
__device__ __forceinline__ float bfw(unsigned u) { return __uint_as_float(u << 16); }
__device__ __forceinline__ float lrelu(float x) { return x > 0.f ? x : 0.2f * x; }
__device__ __forceinline__ unsigned short f2bf(float f) {
  unsigned u = __float_as_uint(f);
  return (unsigned short)((u + 0x7fffu + ((u >> 16) & 1u)) >> 16);
}

// ---------------- CSR build via 2-pass coarse-bucket counting sort ----------------
__global__ __launch_bounds__(256) void bucket_pass1(const int* __restrict__ ei,
                                                    unsigned* __restrict__ staging,
                                                    unsigned* __restrict__ staging2,
                                                    int* __restrict__ gcnt) {
  __shared__ int hist[256];
  __shared__ int lbase[256];
  int t = threadIdx.x;
  hist[t] = 0;
  __syncthreads();
  int base = blockIdx.x * EPB;
  unsigned pk[16];
  int bk[16];
  #pragma unroll
  for (int j = 0; j < 16; ++j) {
    int e = base + j * 256 + t;
    int s, d;
    if (e < EE) { s = ei[e]; d = ei[EE + e]; } else { s = d = e - EE; }
    pk[j] = ((unsigned)s << 8) | (unsigned)(d & 255);
    bk[j] = d >> 8;
    atomicAdd(&hist[bk[j]], 1);
  }
  __syncthreads();
  lbase[t] = atomicAdd(&gcnt[t], hist[t]);   // reserve contiguous chunk per bucket
  __syncthreads();
  #pragma unroll
  for (int j = 0; j < 16; ++j) {
    int e = base + j * 256 + t;
    int pos = atomicAdd(&lbase[bk[j]], 1);
    staging[(size_t)bk[j] * CAPB + pos] = pk[j];
    staging2[(size_t)bk[j] * CAPB + pos] = (unsigned)e;
  }
}

__global__ __launch_bounds__(256) void bucket_pass2(const unsigned* __restrict__ staging,
                                                    const unsigned* __restrict__ staging2,
                                                    const int* __restrict__ gcnt,
                                                    int* __restrict__ row_ptr,
                                                    unsigned short* __restrict__ col,
                                                    int* __restrict__ orig) {
  __shared__ int pref[256];
  __shared__ int hist[256];
  __shared__ int loc[256];
  __shared__ int cnt2[256];
  __shared__ unsigned lin[CAPB];
  __shared__ unsigned short lout[CAPB];
  __shared__ int lorig[CAPB];
  int t = threadIdx.x, b = blockIdx.x;

  pref[t] = gcnt[t];
  hist[t] = 0;
  __syncthreads();
  for (int off = 1; off < 256; off <<= 1) {      // inclusive scan of bucket counts
    int v = (t >= off) ? pref[t - off] : 0;
    __syncthreads();
    pref[t] += v;
    __syncthreads();
  }
  int rowbase = (b > 0) ? pref[b - 1] : 0;
  int nb = gcnt[b];

  for (int i = t; i < nb; i += 256) {
    unsigned v = staging[(size_t)b * CAPB + i];
    lin[i] = v;
    atomicAdd(&hist[v & 255], 1);
  }
  __syncthreads();
  loc[t] = hist[t];
  __syncthreads();
  for (int off = 1; off < 256; off <<= 1) {      // inclusive scan of local hist
    int v = (t >= off) ? loc[t - off] : 0;
    __syncthreads();
    loc[t] += v;
    __syncthreads();
  }
  int excl = loc[t] - hist[t];
  row_ptr[b * 256 + t] = rowbase + excl;
  cnt2[t] = excl;
  if (b == 255 && t == 255) row_ptr[NN] = rowbase + nb;
  __syncthreads();
  for (int i = t; i < nb; i += 256) {
    unsigned v = lin[i];
    int r = atomicAdd(&cnt2[v & 255], 1);
    lout[r] = (unsigned short)(v >> 8);
    lorig[r] = (int)staging2[(size_t)b * CAPB + i];
  }
  __syncthreads();
  for (int i = t; i < nb; i += 256) {            // coalesced final writes
    col[rowbase + i] = lout[i];
    orig[rowbase + i] = lorig[i];
  }
}

// -------- dense: h = x@W, al_s/al_d, residual; register-blocked over nodes --------
template<int DIN, int DOUT, int H, bool HAS_RES, int NPW>
__global__ __launch_bounds__(256) void gemm_al_kernel(
    const float* __restrict__ xin, const float* __restrict__ W,
    const float* __restrict__ asrc, const float* __restrict__ adst,
    const float* __restrict__ Aw, const float* __restrict__ Ab,
    unsigned short* __restrict__ hw16, float* __restrict__ res,
    float* __restrict__ als, float* __restrict__ ald)
{
  constexpr int GPW = 64 / DOUT;
  constexpr int NPB = 4 * NPW * GPW;   // nodes per block (4 waves)
  constexpr int DINP = DIN + 4;        // padded LDS stride
  __shared__ float xs[NPB][DINP];

  int wave = threadIdx.x >> 6;
  int lane = threadIdx.x & 63;
  int l = lane % DOUT;
  int sub = lane / DOUT;
  int block_base = blockIdx.x * NPB;

  {
    constexpr int NV = NPB * DIN / 4;
    const float4* xin4 = (const float4*)(xin + (size_t)block_base * DIN);
    for (int i = threadIdx.x; i < NV; i += 256) {
      float4 v = xin4[i];
      int flat = i * 4;
      int nd = flat / DIN, k = flat % DIN;
      *(float4*)&xs[nd][k] = v;
    }
  }
  __syncthreads();

  int nl = wave * (NPW * GPW) + sub * NPW;
  float acc[NPW], racc[NPW];
  #pragma unroll
  for (int n = 0; n < NPW; ++n) { acc[n] = 0.f; racc[n] = 0.f; }

  for (int k = 0; k < DIN; k += 4) {
    float w0 = W[(k + 0) * DOUT + l];
    float w1 = W[(k + 1) * DOUT + l];
    float w2 = W[(k + 2) * DOUT + l];
    float w3 = W[(k + 3) * DOUT + l];
    float a0 = 0.f, a1 = 0.f, a2 = 0.f, a3 = 0.f;
    if (HAS_RES) {
      a0 = Aw[(k + 0) * DOUT + l];
      a1 = Aw[(k + 1) * DOUT + l];
      a2 = Aw[(k + 2) * DOUT + l];
      a3 = Aw[(k + 3) * DOUT + l];
    }
    #pragma unroll
    for (int n = 0; n < NPW; ++n) {
      float4 xv = *(const float4*)&xs[nl + n][k];
      acc[n] = fmaf(xv.x, w0, fmaf(xv.y, w1, fmaf(xv.z, w2, fmaf(xv.w, w3, acc[n]))));
      if (HAS_RES)
        racc[n] = fmaf(xv.x, a0, fmaf(xv.y, a1, fmaf(xv.z, a2, fmaf(xv.w, a3, racc[n]))));
    }
  }

  int head = l >> 2, c = l & 3;
  float sa = asrc[l];
  float da = adst[l];
  #pragma unroll
  for (int n = 0; n < NPW; ++n) {
    size_t node = (size_t)(block_base + nl + n);
    float hh = acc[n];
    hw16[node * DOUT + l] = f2bf(hh);
    if (HAS_RES) res[node * DOUT + l] = racc[n] + Ab[l];
    float ps = hh * sa, pd = hh * da;
    ps += __shfl_xor(ps, 1); ps += __shfl_xor(ps, 2);
    pd += __shfl_xor(pd, 1); pd += __shfl_xor(pd, 2);
    if (c == 0) {
      als[node * H + head] = ps;
      ald[node * H + head] = pd;
    }
  }
}

// -------- fused gather: softmax-agg + LN epilogue + CSR-order amean + exp-sum --------
template<int DOUT, int H, bool HAS_RES>
__global__ __launch_bounds__(256) void gat_gather_kernel(
    const int* __restrict__ row_ptr, const unsigned short* __restrict__ col,
    const int* __restrict__ orig,
    const float* __restrict__ als, const float* __restrict__ ald,
    const unsigned* __restrict__ hw2,   // bf16x2: channels (2l, 2l+1)
    const float* __restrict__ bias, const float* __restrict__ g,
    const float* __restrict__ be, const float* __restrict__ res,
    float* __restrict__ out, unsigned short* __restrict__ am_csr,
    float* __restrict__ ssum)
{
  constexpr int G = DOUT / 2;          // lanes per node
  constexpr int NPBLK = 256 / G;       // nodes per block
  __shared__ float s_ald[NPBLK][H];
  __shared__ float s_inv[NPBLK][H];
  __shared__ float red[4];

  int tid = blockIdx.x * 256 + threadIdx.x;
  int node = tid / G;
  int l = threadIdx.x % G;             // group lane: channels 2l, 2l+1
  int h = l >> 1;                      // head (2 lanes per head)
  int nloc = threadIdx.x / G;

  int r0 = row_ptr[node], r1 = row_ptr[node + 1];
  float ald_h = ald[node * H + h];

  float acc0 = 0.f, acc1 = 0.f, ss = 0.f;
  int e = r0;
  for (; e + 3 < r1; e += 4) {
    int s0 = col[e], s1 = col[e + 1], s2 = col[e + 2], s3 = col[e + 3];
    float av0 = als[s0 * H + h];
    float av1 = als[s1 * H + h];
    float av2 = als[s2 * H + h];
    float av3 = als[s3 * H + h];
    unsigned p0 = hw2[s0 * G + l];
    unsigned p1 = hw2[s1 * G + l];
    unsigned p2 = hw2[s2 * G + l];
    unsigned p3 = hw2[s3 * G + l];
    float lg0 = lrelu(av0 + ald_h);
    float lg1 = lrelu(av1 + ald_h);
    float lg2 = lrelu(av2 + ald_h);
    float lg3 = lrelu(av3 + ald_h);
    float e0 = __expf(lg0), e1 = __expf(lg1), e2 = __expf(lg2), e3 = __expf(lg3);
    ss += (e0 + e1) + (e2 + e3);
    acc0 += e0 * bflo(p0) + e1 * bflo(p1) + e2 * bflo(p2) + e3 * bflo(p3);
    acc1 += e0 * bfhi(p0) + e1 * bfhi(p1) + e2 * bfhi(p2) + e3 * bfhi(p3);
  }
  for (; e < r1; ++e) {
    int s0 = col[e];
    float av0 = als[s0 * H + h];
    unsigned p0 = hw2[s0 * G + l];
    float lg0 = lrelu(av0 + ald_h);
    float e0 = __expf(lg0);
    ss += e0;
    acc0 += e0 * bflo(p0);
    acc1 += e0 * bfhi(p0);
  }

  float inv = 1.f / ss;                // identical across the 2 lanes of a head
  if ((l & 1) == 0) { s_ald[nloc][h] = ald_h; s_inv[nloc][h] = inv; }

  // epilogue: normalize -> bias -> elu -> layernorm -> (+res), 2 channels/lane
  float2 bb = ((const float2*)bias)[l];
  float v0 = acc0 * inv + bb.x;
  float v1 = acc1 * inv + bb.y;
  v0 = v0 > 0.f ? v0 : expm1f(v0);
  v1 = v1 > 0.f ? v1 : expm1f(v1);
  float sum = v0 + v1;
  #pragma unroll
  for (int o = G / 2; o; o >>= 1) sum += __shfl_xor(sum, o);
  float mu = sum * (1.f / DOUT);
  float d0 = v0 - mu, d1 = v1 - mu;
  float vs = d0 * d0 + d1 * d1;
  #pragma unroll
  for (int o = G / 2; o; o >>= 1) vs += __shfl_xor(vs, o);
  float rstd = rsqrtf(vs * (1.f / DOUT) + 1e-5f);
  float2 gg = ((const float2*)g)[l];
  float2 ee = ((const float2*)be)[l];
  float y0 = d0 * rstd * gg.x + ee.x;
  float y1 = d1 * rstd * gg.y + ee.y;
  if (HAS_RES) {
    float2 rr = ((const float2*)res)[node * G + l];
    y0 += rr.x; y1 += rr.y;
  }
  ((float2*)out)[node * G + l] = make_float2(y0, y1);

  __syncthreads();   // s_ald / s_inv visible block-wide

  // second pass: per-edge head-mean alpha in CSR order (coalesced am_csr writes)
  float ex = 0.f;
  for (int e2 = r0 + l; e2 < r1; e2 += G) {
    int s = col[e2];
    const float4* a4 = (const float4*)(als + (size_t)s * H);
    float t = 0.f;
    #pragma unroll
    for (int q = 0; q < H / 4; ++q) {
      float4 av = a4[q];
      t += __expf(lrelu(av.x + s_ald[nloc][4 * q + 0])) * s_inv[nloc][4 * q + 0];
      t += __expf(lrelu(av.y + s_ald[nloc][4 * q + 1])) * s_inv[nloc][4 * q + 1];
      t += __expf(lrelu(av.z + s_ald[nloc][4 * q + 2])) * s_inv[nloc][4 * q + 2];
      t += __expf(lrelu(av.w + s_ald[nloc][4 * q + 3])) * s_inv[nloc][4 * q + 3];
    }
    t *= (1.f / H);
    unsigned short tb = f2bf(t);
    am_csr[e2] = tb;
    if (orig[e2] < EE) ex += __expf(bfw(tb));  // exclude self-loop slots
  }
  #pragma unroll
  for (int o = 32; o; o >>= 1) ex += __shfl_xor(ex, o);
  if ((threadIdx.x & 63) == 0) red[threadIdx.x >> 6] = ex;
  __syncthreads();
  if (threadIdx.x == 0) atomicAdd(ssum, (red[0] + red[1]) + (red[2] + red[3]));
}

// ---- pack: CSR-order read of orig + 3x bf16 amean, bucket-stage by edge id ----
__global__ __launch_bounds__(256) void pack_pass(
    const int* __restrict__ orig,
    const unsigned short* __restrict__ am1, const unsigned short* __restrict__ am2,
    const unsigned short* __restrict__ am3,
    unsigned long long* __restrict__ pstag, int* __restrict__ gcnt2)
{
  __shared__ int hist[256];
  __shared__ int lbase[256];
  int t = threadIdx.x;
  hist[t] = 0;
  __syncthreads();
  int base = blockIdx.x * EPB;
  unsigned long long pk[16];
  int bk[16];
  bool va[16];
  #pragma unroll
  for (int j = 0; j < 16; ++j) {
    int i = base + j * 256 + t;
    int oe = orig[i];
    va[j] = (oe < EE);
    bk[j] = oe >> 12;
    pk[j] = ((unsigned long long)(oe & 4095) << 48) |
            ((unsigned long long)am3[i] << 32) |
            ((unsigned long long)am2[i] << 16) |
            (unsigned long long)am1[i];
    if (va[j]) atomicAdd(&hist[bk[j]], 1);
  }
  __syncthreads();
  lbase[t] = atomicAdd(&gcnt2[t], hist[t]);
  __syncthreads();
  #pragma unroll
  for (int j = 0; j < 16; ++j) {
    if (va[j]) {
      int pos = atomicAdd(&lbase[bk[j]], 1);
      pstag[(size_t)bk[j] * 4096 + pos] = pk[j];
    }
  }
}

// ---- unpack: LDS unbucket, apply softmax scale, fully coalesced e-output writes ----
__global__ __launch_bounds__(256) void unpack_pass(
    const unsigned long long* __restrict__ pstag, const float* __restrict__ ssum,
    float* __restrict__ oute1, float* __restrict__ oute2, float* __restrict__ oute3)
{
  __shared__ float a1[4096], a2[4096], a3[4096];
  int t = threadIdx.x, b = blockIdx.x;
  float i1 = 1.f / ssum[0], i2 = 1.f / ssum[1], i3 = 1.f / ssum[2];
  for (int k = t; k < 4096; k += 256) {
    unsigned long long v = pstag[(size_t)b * 4096 + k];
    int idx = (int)(v >> 48);
    a1[idx] = __expf(bfw((unsigned)(v & 0xffffu))) * i1;
    a2[idx] = __expf(bfw((unsigned)((v >> 16) & 0xffffu))) * i2;
    a3[idx] = __expf(bfw((unsigned)((v >> 32) & 0xffffu))) * i3;
  }
  __syncthreads();
  size_t base = (size_t)b * 4096;
  for (int k = t; k < 4096; k += 256) {
    oute1[base + k] = a1[k];
    oute2[base + k] = a2[k];
    oute3[base + k] = a3[k];
  }
}

// ---------------- per-layer driver ----------------
template<int DIN, int DOUT, int H, bool HAS_RES>
static void run_layer(const float* xin, const float* W, const float* as_,
                      const float* ad_, const float* bias, const float* Aw,
                      const float* Ab, const float* g, const float* be,
                      const int* row_ptr, const unsigned short* col, const int* orig,
                      unsigned short* hw16, float* res, float* als, float* ald,
                      unsigned short* am_csr, float* ssum,
                      float* hout, hipStream_t stream)
{
  constexpr int NPW = 8;
  constexpr int NPB = 4 * NPW * (64 / DOUT);
  constexpr int G = DOUT / 2;
  gemm_al_kernel<DIN, DOUT, H, HAS_RES, NPW><<<NN / NPB, 256, 0, stream>>>(
      xin, W, as_, ad_, Aw, Ab, hw16, res, als, ald);
  gat_gather_kernel<DOUT, H, HAS_RES><<<(NN * G) / 256, 256, 0, stream>>>(
      row_ptr, col, orig, als, ald, (const unsigned*)hw16, bias, g, be, res,
      hout, am_csr, ssum);
}

extern "C" void kernel_launch(void* const* d_in, const int* in_sizes, int n_in,
                              void* d_out, int out_size, void* d_ws, size_t ws_size,
                              hipStream_t stream)
{
  const float* x   = (const float*)d_in[0];
  const int*   ei  = (const int*)d_in[1];
  const float* W1  = (const float*)d_in[3];
  const float* as1 = (const float*)d_in[4];
  const float* ad1 = (const float*)d_in[5];
  const float* b1  = (const float*)d_in[6];
  const float* W2  = (const float*)d_in[7];
  const float* as2 = (const float*)d_in[8];
  const float* ad2 = (const float*)d_in[9];
  const float* b2  = (const float*)d_in[10];
  const float* W3  = (const float*)d_in[11];
  const float* as3 = (const float*)d_in[12];
  const float* ad3 = (const float*)d_in[13];
  const float* b3  = (const float*)d_in[14];
  const float* A1w = (const float*)d_in[15];
  const float* A1b = (const float*)d_in[16];
  const float* A2w = (const float*)d_in[17];
  const float* A2b = (const float*)d_in[18];
  const float* g1  = (const float*)d_in[19];
  const float* be1 = (const float*)d_in[20];
  const float* g2  = (const float*)d_in[21];
  const float* be2 = (const float*)d_in[22];
  const float* g3  = (const float*)d_in[23];
  const float* be3 = (const float*)d_in[24];

  float* ws = (float*)d_ws;
  size_t off = 0;
  float* h1       = ws + off; off += (size_t)NN * 64;
  float* h2       = ws + off; off += (size_t)NN * 32;
  unsigned short* hw16 = (unsigned short*)(ws + off); off += (size_t)NN * 32;
  float* res      = ws + off; off += (size_t)NN * 64;
  float* als      = ws + off; off += (size_t)NN * 16;
  float* ald      = ws + off; off += (size_t)NN * 16;
  unsigned short* am1c = (unsigned short*)(ws + off); off += (size_t)ET / 2 + 4;
  unsigned short* am2c = (unsigned short*)(ws + off); off += (size_t)ET / 2 + 4;
  unsigned short* am3c = (unsigned short*)(ws + off); off += (size_t)ET / 2 + 4;
  float* scal     = ws + off; off += 16;
  int* row_ptr    = (int*)(ws + off); off += NN + 4;
  unsigned short* col = (unsigned short*)(ws + off); off += (size_t)ET / 2 + 4;
  int* orig       = (int*)(ws + off); off += ET;
  int* gcnt       = (int*)(ws + off); off += 256;
  int* gcnt2      = (int*)(ws + off); off += 256;
  unsigned* staging  = (unsigned*)(ws + off); off += (size_t)256 * CAPB;
  unsigned* staging2 = (unsigned*)(ws + off); off += (size_t)256 * CAPB;
  if (off & 1) off++;  // 8B align
  unsigned long long* pstag = (unsigned long long*)(ws + off); off += (size_t)EE * 2;

  float* outh3 = (float*)d_out;
  float* oute1 = outh3 + (size_t)NN * 16;
  float* oute2 = oute1 + EE;
  float* oute3 = oute2 + EE;

  // ---- CSR build via coarse-bucket sort (graph-capture safe) ----
  hipMemsetAsync(gcnt, 0, 512 * sizeof(int), stream);   // gcnt + gcnt2 (adjacent)
  hipMemsetAsync(scal, 0, 16, stream);
  bucket_pass1<<<P1B, 256, 0, stream>>>(ei, staging, staging2, gcnt);
  bucket_pass2<<<256, 256, 0, stream>>>(staging, staging2, gcnt, row_ptr, col, orig);

  run_layer<84, 64, 16, true>(x, W1, as1, ad1, b1, A1w, A1b, g1, be1,
                              row_ptr, col, orig, hw16, res, als, ald,
                              am1c, scal + 0, h1, stream);
  run_layer<64, 32, 8, true>(h1, W2, as2, ad2, b2, A2w, A2b, g2, be2,
                             row_ptr, col, orig, hw16, res, als, ald,
                             am2c, scal + 1, h2, stream);
  run_layer<32, 16, 4, false>(h2, W3, as3, ad3, b3, nullptr, nullptr, g3, be3,
                              row_ptr, col, orig, hw16, res, als, ald,
                              am3c, scal + 2, outh3, stream);

  pack_pass<<<ET / EPB, 256, 0, stream>>>(orig, am1c, am2c, am3c, pstag, gcnt2);
  unpack_pass<<<256, 256, 0, stream>>>(pstag, scal, oute1, oute2, oute3);
}

// Round 11
// 245.322 us; speedup vs baseline: 1.5374x; 1.4814x over previous
//
#include <hip/hip_runtime.h>
#include <math.h>

#define NN 65536
#define EE 1048576
#define ET (EE + NN)

#define CAPB 5120          // staging capacity per coarse bucket (mean 4352, +11.6 sigma)
#define EPB 4096           // edges per pass-1 block
#define P1B (ET / EPB)     // 272 blocks

__device__ __forceinline__ float bflo(unsigned u) { return __uint_as_float(u << 16); }
__device__ __forceinline__ float bfhi(unsigned u) { return __uint_as_float(u & 0xffff0000u); }
__device__ __forceinline__ float bfw(unsigned u) { return __uint_as_float(u << 16); }
__device__ __forceinline__ float lrelu(float x) { return x > 0.f ? x : 0.2f * x; }
__device__ __forceinline__ unsigned short f2bf(float f) {
  unsigned u = __float_as_uint(f);
  return (unsigned short)((u + 0x7fffu + ((u >> 16) & 1u)) >> 16);
}

// ---------------- CSR build via 2-pass coarse-bucket counting sort ----------------
__global__ __launch_bounds__(256) void bucket_pass1(const int* __restrict__ ei,
                                                    unsigned* __restrict__ staging,
                                                    unsigned* __restrict__ staging2,
                                                    int* __restrict__ gcnt) {
  __shared__ int hist[256];
  __shared__ int lbase[256];
  int t = threadIdx.x;
  hist[t] = 0;
  __syncthreads();
  int base = blockIdx.x * EPB;
  unsigned pk[16];
  int bk[16];
  #pragma unroll
  for (int j = 0; j < 16; ++j) {
    int e = base + j * 256 + t;
    int s, d;
    if (e < EE) { s = ei[e]; d = ei[EE + e]; } else { s = d = e - EE; }
    pk[j] = ((unsigned)s << 8) | (unsigned)(d & 255);
    bk[j] = d >> 8;
    atomicAdd(&hist[bk[j]], 1);
  }
  __syncthreads();
  lbase[t] = atomicAdd(&gcnt[t], hist[t]);   // reserve contiguous chunk per bucket
  __syncthreads();
  #pragma unroll
  for (int j = 0; j < 16; ++j) {
    int e = base + j * 256 + t;
    int pos = atomicAdd(&lbase[bk[j]], 1);
    staging[(size_t)bk[j] * CAPB + pos] = pk[j];
    staging2[(size_t)bk[j] * CAPB + pos] = (unsigned)e;
  }
}

__global__ __launch_bounds__(256) void bucket_pass2(const unsigned* __restrict__ staging,
                                                    const unsigned* __restrict__ staging2,
                                                    const int* __restrict__ gcnt,
                                                    int* __restrict__ row_ptr,
                                                    unsigned short* __restrict__ col,
                                                    unsigned short* __restrict__ dste,
                                                    int* __restrict__ orig) {
  __shared__ int pref[256];
  __shared__ int hist[256];
  __shared__ int loc[256];
  __shared__ int cnt2[256];
  __shared__ unsigned lin[CAPB];
  __shared__ unsigned lout[CAPB];
  __shared__ int lorig[CAPB];
  int t = threadIdx.x, b = blockIdx.x;

  pref[t] = gcnt[t];
  hist[t] = 0;
  __syncthreads();
  for (int off = 1; off < 256; off <<= 1) {      // inclusive scan of bucket counts
    int v = (t >= off) ? pref[t - off] : 0;
    __syncthreads();
    pref[t] += v;
    __syncthreads();
  }
  int rowbase = (b > 0) ? pref[b - 1] : 0;
  int nb = gcnt[b];

  for (int i = t; i < nb; i += 256) {
    unsigned v = staging[(size_t)b * CAPB + i];
    lin[i] = v;
    atomicAdd(&hist[v & 255], 1);
  }
  __syncthreads();
  loc[t] = hist[t];
  __syncthreads();
  for (int off = 1; off < 256; off <<= 1) {      // inclusive scan of local hist
    int v = (t >= off) ? loc[t - off] : 0;
    __syncthreads();
    loc[t] += v;
    __syncthreads();
  }
  int excl = loc[t] - hist[t];
  row_ptr[b * 256 + t] = rowbase + excl;
  cnt2[t] = excl;
  if (b == 255 && t == 255) row_ptr[NN] = rowbase + nb;
  __syncthreads();
  for (int i = t; i < nb; i += 256) {
    unsigned v = lin[i];
    int r = atomicAdd(&cnt2[v & 255], 1);
    lout[r] = v;
    lorig[r] = (int)staging2[(size_t)b * CAPB + i];
  }
  __syncthreads();
  for (int i = t; i < nb; i += 256) {            // coalesced final writes
    unsigned v = lout[i];
    col[rowbase + i] = (unsigned short)(v >> 8);
    dste[rowbase + i] = (unsigned short)(b * 256 + (v & 255));
    orig[rowbase + i] = lorig[i];
  }
}

// -------- dense: h = x@W, al_s/al_d, residual; register-blocked over nodes --------
// writes f32 als/ald for gather + bf16 combo rows (cs: als, cd: ald) for amean.
template<int DIN, int DOUT, int H, bool HAS_RES, int NPW, int CS_OFF, int ALD_OFF>
__global__ __launch_bounds__(256) void gemm_al_kernel(
    const float* __restrict__ xin, const float* __restrict__ W,
    const float* __restrict__ asrc, const float* __restrict__ adst,
    const float* __restrict__ Aw, const float* __restrict__ Ab,
    unsigned short* __restrict__ hw16, float* __restrict__ res,
    float* __restrict__ als, float* __restrict__ ald,
    unsigned short* __restrict__ cs, unsigned short* __restrict__ cd)
{
  constexpr int GPW = 64 / DOUT;
  constexpr int NPB = 4 * NPW * GPW;   // nodes per block (4 waves)
  constexpr int DINP = DIN + 4;        // padded LDS stride
  __shared__ float xs[NPB][DINP];

  int wave = threadIdx.x >> 6;
  int lane = threadIdx.x & 63;
  int l = lane % DOUT;
  int sub = lane / DOUT;
  int block_base = blockIdx.x * NPB;

  {
    constexpr int NV = NPB * DIN / 4;
    const float4* xin4 = (const float4*)(xin + (size_t)block_base * DIN);
    for (int i = threadIdx.x; i < NV; i += 256) {
      float4 v = xin4[i];
      int flat = i * 4;
      int nd = flat / DIN, k = flat % DIN;
      *(float4*)&xs[nd][k] = v;
    }
  }
  __syncthreads();

  int nl = wave * (NPW * GPW) + sub * NPW;
  float acc[NPW], racc[NPW];
  #pragma unroll
  for (int n = 0; n < NPW; ++n) { acc[n] = 0.f; racc[n] = 0.f; }

  for (int k = 0; k < DIN; k += 4) {
    float w0 = W[(k + 0) * DOUT + l];
    float w1 = W[(k + 1) * DOUT + l];
    float w2 = W[(k + 2) * DOUT + l];
    float w3 = W[(k + 3) * DOUT + l];
    float a0 = 0.f, a1 = 0.f, a2 = 0.f, a3 = 0.f;
    if (HAS_RES) {
      a0 = Aw[(k + 0) * DOUT + l];
      a1 = Aw[(k + 1) * DOUT + l];
      a2 = Aw[(k + 2) * DOUT + l];
      a3 = Aw[(k + 3) * DOUT + l];
    }
    #pragma unroll
    for (int n = 0; n < NPW; ++n) {
      float4 xv = *(const float4*)&xs[nl + n][k];
      acc[n] = fmaf(xv.x, w0, fmaf(xv.y, w1, fmaf(xv.z, w2, fmaf(xv.w, w3, acc[n]))));
      if (HAS_RES)
        racc[n] = fmaf(xv.x, a0, fmaf(xv.y, a1, fmaf(xv.z, a2, fmaf(xv.w, a3, racc[n]))));
    }
  }

  int head = l >> 2, c = l & 3;
  float sa = asrc[l];
  float da = adst[l];
  #pragma unroll
  for (int n = 0; n < NPW; ++n) {
    size_t node = (size_t)(block_base + nl + n);
    float hh = acc[n];
    hw16[node * DOUT + l] = f2bf(hh);
    if (HAS_RES) res[node * DOUT + l] = racc[n] + Ab[l];
    float ps = hh * sa, pd = hh * da;
    ps += __shfl_xor(ps, 1); ps += __shfl_xor(ps, 2);
    pd += __shfl_xor(pd, 1); pd += __shfl_xor(pd, 2);
    if (c == 0) {
      als[node * H + head] = ps;
      ald[node * H + head] = pd;
      cs[node * 32 + CS_OFF + head] = f2bf(ps);
      cd[node * 64 + ALD_OFF + head] = f2bf(pd);
    }
  }
}

// ---------------- fused gather: bf16x2 channels, DOUT/2 lanes per node ----------------
template<int DOUT, int H, bool HAS_RES, int INV_OFF>
__global__ __launch_bounds__(256) void gat_gather_kernel(
    const int* __restrict__ row_ptr, const unsigned short* __restrict__ col,
    const float* __restrict__ als, const float* __restrict__ ald,
    const unsigned* __restrict__ hw2,   // bf16x2: channels (2l, 2l+1)
    const float* __restrict__ bias, const float* __restrict__ g,
    const float* __restrict__ be, const float* __restrict__ res,
    float* __restrict__ out, unsigned short* __restrict__ cd)
{
  constexpr int G = DOUT / 2;          // lanes per node
  int tid = blockIdx.x * 256 + threadIdx.x;
  int node = tid / G;
  int l = threadIdx.x % G;             // group lane: channels 2l, 2l+1
  int h = l >> 1;                      // head (2 lanes per head)

  int r0 = row_ptr[node], r1 = row_ptr[node + 1];
  float ald_h = ald[node * H + h];

  float acc0 = 0.f, acc1 = 0.f, ss = 0.f;
  int e = r0;
  for (; e + 3 < r1; e += 4) {
    int s0 = col[e], s1 = col[e + 1], s2 = col[e + 2], s3 = col[e + 3];
    float av0 = als[s0 * H + h];
    float av1 = als[s1 * H + h];
    float av2 = als[s2 * H + h];
    float av3 = als[s3 * H + h];
    unsigned p0 = hw2[s0 * G + l];
    unsigned p1 = hw2[s1 * G + l];
    unsigned p2 = hw2[s2 * G + l];
    unsigned p3 = hw2[s3 * G + l];
    float lg0 = lrelu(av0 + ald_h);
    float lg1 = lrelu(av1 + ald_h);
    float lg2 = lrelu(av2 + ald_h);
    float lg3 = lrelu(av3 + ald_h);
    float e0 = __expf(lg0), e1 = __expf(lg1), e2 = __expf(lg2), e3 = __expf(lg3);
    ss += (e0 + e1) + (e2 + e3);
    acc0 += e0 * bflo(p0) + e1 * bflo(p1) + e2 * bflo(p2) + e3 * bflo(p3);
    acc1 += e0 * bfhi(p0) + e1 * bfhi(p1) + e2 * bfhi(p2) + e3 * bfhi(p3);
  }
  for (; e < r1; ++e) {
    int s0 = col[e];
    float av0 = als[s0 * H + h];
    unsigned p0 = hw2[s0 * G + l];
    float lg0 = lrelu(av0 + ald_h);
    float e0 = __expf(lg0);
    ss += e0;
    acc0 += e0 * bflo(p0);
    acc1 += e0 * bfhi(p0);
  }

  float inv = 1.f / ss;                // identical across the 2 lanes of a head
  if ((l & 1) == 0) cd[node * 64 + INV_OFF + h] = f2bf(inv);

  // epilogue: normalize -> bias -> elu -> layernorm -> (+res), 2 channels/lane
  float2 bb = ((const float2*)bias)[l];
  float v0 = acc0 * inv + bb.x;
  float v1 = acc1 * inv + bb.y;
  v0 = v0 > 0.f ? v0 : expm1f(v0);
  v1 = v1 > 0.f ? v1 : expm1f(v1);
  float sum = v0 + v1;
  #pragma unroll
  for (int o = G / 2; o; o >>= 1) sum += __shfl_xor(sum, o);
  float mu = sum * (1.f / DOUT);
  float d0 = v0 - mu, d1 = v1 - mu;
  float vs = d0 * d0 + d1 * d1;
  #pragma unroll
  for (int o = G / 2; o; o >>= 1) vs += __shfl_xor(vs, o);
  float rstd = rsqrtf(vs * (1.f / DOUT) + 1e-5f);
  float2 gg = ((const float2*)g)[l];
  float2 ee = ((const float2*)be)[l];
  float y0 = d0 * rstd * gg.x + ee.x;
  float y1 = d1 * rstd * gg.y + ee.y;
  if (HAS_RES) {
    float2 rr = ((const float2*)res)[node * G + l];
    y0 += rr.x; y1 += rr.y;
  }
  ((float2*)out)[node * G + l] = make_float2(y0, y1);
}

// ---- all-layer amean in CSR order + fused bucket-pack by original edge id ----
// s-side: one aligned 64B bf16 cs line per edge (4MB table, L2-resident).
// d-side: 128B bf16 cd rows, run-sequential (dst-sorted) -> L1/L2-hot.
__global__ __launch_bounds__(512) void amean_pack_kernel(
    const unsigned short* __restrict__ col, const unsigned short* __restrict__ dste,
    const int* __restrict__ orig,
    const unsigned* __restrict__ cs, const unsigned* __restrict__ cd,
    unsigned long long* __restrict__ pstag, int* __restrict__ gcnt2,
    float* __restrict__ ssum)
{
  __shared__ int hist[256];
  __shared__ int lbase[256];
  __shared__ float red[3][8];
  int t = threadIdx.x;
  if (t < 256) hist[t] = 0;
  __syncthreads();
  int base = blockIdx.x * EPB;
  unsigned long long pk[8];
  int bk[8];
  bool va[8];
  float ex1 = 0.f, ex2 = 0.f, ex3 = 0.f;
  #pragma unroll
  for (int j = 0; j < 8; ++j) {
    int i = base + j * 512 + t;
    int c = col[i], d = dste[i], oe = orig[i];
    const uint4* csr = (const uint4*)(cs + (size_t)c * 16);
    const uint4* cdr = (const uint4*)(cd + (size_t)d * 32);
    uint4 S0 = csr[0], S1 = csr[1], S2 = csr[2], S3 = csr[3];
    uint4 A0 = cdr[0], A1 = cdr[1], V0 = cdr[2], V1 = cdr[3];
    uint4 A2 = cdr[4], V2 = cdr[5];
    uint4 AV3 = cdr[6];   // x,y = ald3 ; z,w = inv3
    // layer 1 (H=16)
    float t1 = 0.f;
    {
      unsigned S[8] = {S0.x, S0.y, S0.z, S0.w, S1.x, S1.y, S1.z, S1.w};
      unsigned A[8] = {A0.x, A0.y, A0.z, A0.w, A1.x, A1.y, A1.z, A1.w};
      unsigned V[8] = {V0.x, V0.y, V0.z, V0.w, V1.x, V1.y, V1.z, V1.w};
      #pragma unroll
      for (int q = 0; q < 8; ++q) {
        t1 += __expf(lrelu(bflo(S[q]) + bflo(A[q]))) * bflo(V[q])
            + __expf(lrelu(bfhi(S[q]) + bfhi(A[q]))) * bfhi(V[q]);
      }
      t1 *= (1.f / 16.f);
    }
    // layer 2 (H=8)
    float t2 = 0.f;
    {
      unsigned S[4] = {S2.x, S2.y, S2.z, S2.w};
      unsigned A[4] = {A2.x, A2.y, A2.z, A2.w};
      unsigned V[4] = {V2.x, V2.y, V2.z, V2.w};
      #pragma unroll
      for (int q = 0; q < 4; ++q) {
        t2 += __expf(lrelu(bflo(S[q]) + bflo(A[q]))) * bflo(V[q])
            + __expf(lrelu(bfhi(S[q]) + bfhi(A[q]))) * bfhi(V[q]);
      }
      t2 *= (1.f / 8.f);
    }
    // layer 3 (H=4)
    float t3;
    {
      t3 = (__expf(lrelu(bflo(S3.x) + bflo(AV3.x))) * bflo(AV3.z)
          + __expf(lrelu(bfhi(S3.x) + bfhi(AV3.x))) * bfhi(AV3.z)
          + __expf(lrelu(bflo(S3.y) + bflo(AV3.y))) * bflo(AV3.w)
          + __expf(lrelu(bfhi(S3.y) + bfhi(AV3.y))) * bfhi(AV3.w)) * (1.f / 4.f);
    }
    va[j] = (oe < EE);
    bk[j] = oe >> 12;
    pk[j] = ((unsigned long long)(oe & 4095) << 48) |
            ((unsigned long long)f2bf(t3) << 32) |
            ((unsigned long long)f2bf(t2) << 16) |
            (unsigned long long)f2bf(t1);
    if (va[j]) {
      ex1 += __expf(bfw(f2bf(t1)));
      ex2 += __expf(bfw(f2bf(t2)));
      ex3 += __expf(bfw(f2bf(t3)));
      atomicAdd(&hist[bk[j]], 1);
    }
  }
  __syncthreads();
  if (t < 256) lbase[t] = atomicAdd(&gcnt2[t], hist[t]);
  __syncthreads();
  #pragma unroll
  for (int j = 0; j < 8; ++j) {
    if (va[j]) {
      int pos = atomicAdd(&lbase[bk[j]], 1);
      pstag[(size_t)bk[j] * 4096 + pos] = pk[j];
    }
  }
  #pragma unroll
  for (int o = 32; o; o >>= 1) {
    ex1 += __shfl_xor(ex1, o);
    ex2 += __shfl_xor(ex2, o);
    ex3 += __shfl_xor(ex3, o);
  }
  int w = t >> 6;
  if ((t & 63) == 0) { red[0][w] = ex1; red[1][w] = ex2; red[2][w] = ex3; }
  __syncthreads();
  if (t == 0) {
    float s1 = 0.f, s2 = 0.f, s3 = 0.f;
    #pragma unroll
    for (int q = 0; q < 8; ++q) { s1 += red[0][q]; s2 += red[1][q]; s3 += red[2][q]; }
    atomicAdd(&ssum[0], s1);
    atomicAdd(&ssum[1], s2);
    atomicAdd(&ssum[2], s3);
  }
}

// ---- unpack: LDS unbucket, apply softmax scale, fully coalesced e-output writes ----
__global__ __launch_bounds__(256) void unpack_pass(
    const unsigned long long* __restrict__ pstag, const float* __restrict__ ssum,
    float* __restrict__ oute1, float* __restrict__ oute2, float* __restrict__ oute3)
{
  __shared__ float a1[4096], a2[4096], a3[4096];
  int t = threadIdx.x, b = blockIdx.x;
  float i1 = 1.f / ssum[0], i2 = 1.f / ssum[1], i3 = 1.f / ssum[2];
  for (int k = t; k < 4096; k += 256) {
    unsigned long long v = pstag[(size_t)b * 4096 + k];
    int idx = (int)(v >> 48);
    a1[idx] = __expf(bfw((unsigned)(v & 0xffffu))) * i1;
    a2[idx] = __expf(bfw((unsigned)((v >> 16) & 0xffffu))) * i2;
    a3[idx] = __expf(bfw((unsigned)((v >> 32) & 0xffffu))) * i3;
  }
  __syncthreads();
  size_t base = (size_t)b * 4096;
  for (int k = t; k < 4096; k += 256) {
    oute1[base + k] = a1[k];
    oute2[base + k] = a2[k];
    oute3[base + k] = a3[k];
  }
}

// ---------------- per-layer driver ----------------
template<int DIN, int DOUT, int H, bool HAS_RES, int CS_OFF, int ALD_OFF, int INV_OFF>
static void run_layer(const float* xin, const float* W, const float* as_,
                      const float* ad_, const float* bias, const float* Aw,
                      const float* Ab, const float* g, const float* be,
                      const int* row_ptr, const unsigned short* col,
                      unsigned short* hw16, float* res, float* als, float* ald,
                      unsigned short* cs, unsigned short* cd,
                      float* hout, hipStream_t stream)
{
  constexpr int NPW = 8;
  constexpr int NPB = 4 * NPW * (64 / DOUT);
  constexpr int G = DOUT / 2;
  gemm_al_kernel<DIN, DOUT, H, HAS_RES, NPW, CS_OFF, ALD_OFF><<<NN / NPB, 256, 0, stream>>>(
      xin, W, as_, ad_, Aw, Ab, hw16, res, als, ald, cs, cd);
  gat_gather_kernel<DOUT, H, HAS_RES, INV_OFF><<<(NN * G) / 256, 256, 0, stream>>>(
      row_ptr, col, als, ald, (const unsigned*)hw16, bias, g, be, res, hout, cd);
}

extern "C" void kernel_launch(void* const* d_in, const int* in_sizes, int n_in,
                              void* d_out, int out_size, void* d_ws, size_t ws_size,
                              hipStream_t stream)
{
  const float* x   = (const float*)d_in[0];
  const int*   ei  = (const int*)d_in[1];
  const float* W1  = (const float*)d_in[3];
  const float* as1 = (const float*)d_in[4];
  const float* ad1 = (const float*)d_in[5];
  const float* b1  = (const float*)d_in[6];
  const float* W2  = (const float*)d_in[7];
  const float* as2 = (const float*)d_in[8];
  const float* ad2 = (const float*)d_in[9];
  const float* b2  = (const float*)d_in[10];
  const float* W3  = (const float*)d_in[11];
  const float* as3 = (const float*)d_in[12];
  const float* ad3 = (const float*)d_in[13];
  const float* b3  = (const float*)d_in[14];
  const float* A1w = (const float*)d_in[15];
  const float* A1b = (const float*)d_in[16];
  const float* A2w = (const float*)d_in[17];
  const float* A2b = (const float*)d_in[18];
  const float* g1  = (const float*)d_in[19];
  const float* be1 = (const float*)d_in[20];
  const float* g2  = (const float*)d_in[21];
  const float* be2 = (const float*)d_in[22];
  const float* g3  = (const float*)d_in[23];
  const float* be3 = (const float*)d_in[24];

  float* ws = (float*)d_ws;
  size_t off = 0;
  float* h1       = ws + off; off += (size_t)NN * 64;
  float* h2       = ws + off; off += (size_t)NN * 32;
  unsigned short* hw16 = (unsigned short*)(ws + off); off += (size_t)NN * 32;
  float* res      = ws + off; off += (size_t)NN * 64;
  float* als      = ws + off; off += (size_t)NN * 16;
  float* ald      = ws + off; off += (size_t)NN * 16;
  unsigned short* cs = (unsigned short*)(ws + off); off += (size_t)NN * 16;  // 32 bf16/node
  unsigned short* cd = (unsigned short*)(ws + off); off += (size_t)NN * 32;  // 64 bf16/node
  float* scal     = ws + off; off += 16;
  int* row_ptr    = (int*)(ws + off); off += NN + 4;
  unsigned short* col  = (unsigned short*)(ws + off); off += (size_t)ET / 2 + 4;
  unsigned short* dste = (unsigned short*)(ws + off); off += (size_t)ET / 2 + 4;
  int* orig       = (int*)(ws + off); off += ET;
  int* gcnt       = (int*)(ws + off); off += 256;
  int* gcnt2      = (int*)(ws + off); off += 256;
  unsigned* staging  = (unsigned*)(ws + off); off += (size_t)256 * CAPB;
  unsigned* staging2 = (unsigned*)(ws + off); off += (size_t)256 * CAPB;
  if (off & 1) off++;  // 8B align
  unsigned long long* pstag = (unsigned long long*)(ws + off); off += (size_t)EE * 2;

  float* outh3 = (float*)d_out;
  float* oute1 = outh3 + (size_t)NN * 16;
  float* oute2 = oute1 + EE;
  float* oute3 = oute2 + EE;

  // ---- CSR build via coarse-bucket sort (graph-capture safe) ----
  hipMemsetAsync(gcnt, 0, 512 * sizeof(int), stream);   // gcnt + gcnt2 (adjacent)
  hipMemsetAsync(scal, 0, 16, stream);
  bucket_pass1<<<P1B, 256, 0, stream>>>(ei, staging, staging2, gcnt);
  bucket_pass2<<<256, 256, 0, stream>>>(staging, staging2, gcnt, row_ptr, col, dste, orig);

  // combo layout (bf16 units): cs row 32/node: L1@0 L2@16 L3@24
  // cd row 64/node: ald1@0 inv1@16 ald2@32 inv2@40 ald3@48 inv3@52
  run_layer<84, 64, 16, true, 0, 0, 16>(x, W1, as1, ad1, b1, A1w, A1b, g1, be1,
                                        row_ptr, col, hw16, res, als, ald,
                                        cs, cd, h1, stream);
  run_layer<64, 32, 8, true, 16, 32, 40>(h1, W2, as2, ad2, b2, A2w, A2b, g2, be2,
                                         row_ptr, col, hw16, res, als, ald,
                                         cs, cd, h2, stream);
  run_layer<32, 16, 4, false, 24, 48, 52>(h2, W3, as3, ad3, b3, nullptr, nullptr, g3, be3,
                                          row_ptr, col, hw16, res, als, ald,
                                          cs, cd, outh3, stream);

  amean_pack_kernel<<<ET / EPB, 512, 0, stream>>>(
      col, dste, orig, (const unsigned*)cs, (const unsigned*)cd, pstag, gcnt2, scal);
  unpack_pass<<<256, 256, 0, stream>>>(pstag, scal, oute1, oute2, oute3);
}

// Round 12
// 245.252 us; speedup vs baseline: 1.5378x; 1.0003x over previous
//
#include <hip/hip_runtime.h>
#include <math.h>

#define NN 65536
#define EE 1048576
#define ET (EE + NN)

#define CAPB 5120          // staging capacity per coarse bucket (mean 4352, +11.6 sigma)
#define EPB 4096           // edges per pass-1 block
#define P1B (ET / EPB)     // 272 blocks

#define EPP 2048           // edges per amean_pack block (544 blocks, 4/thread)

__device__ __forceinline__ float bflo(unsigned u) { return __uint_as_float(u << 16); }
__device__ __forceinline__ float bfhi(unsigned u) { return __uint_as_float(u & 0xffff0000u); }
__device__ __forceinline__ float bfw(unsigned u) { return __uint_as_float(u << 16); }
__device__ __forceinline__ float lrelu(float x) { return x > 0.f ? x : 0.2f * x; }
__device__ __forceinline__ unsigned short f2bf(float f) {
  unsigned u = __float_as_uint(f);
  return (unsigned short)((u + 0x7fffu + ((u >> 16) & 1u)) >> 16);
}

// ---------------- CSR build via 2-pass coarse-bucket counting sort ----------------
__global__ __launch_bounds__(256) void bucket_pass1(const int* __restrict__ ei,
                                                    unsigned* __restrict__ staging,
                                                    unsigned* __restrict__ staging2,
                                                    int* __restrict__ gcnt) {
  __shared__ int hist[256];
  __shared__ int lbase[256];
  int t = threadIdx.x;
  hist[t] = 0;
  __syncthreads();
  int base = blockIdx.x * EPB;
  unsigned pk[16];
  int bk[16];
  #pragma unroll
  for (int j = 0; j < 16; ++j) {
    int e = base + j * 256 + t;
    int s, d;
    if (e < EE) { s = ei[e]; d = ei[EE + e]; } else { s = d = e - EE; }
    pk[j] = ((unsigned)s << 8) | (unsigned)(d & 255);
    bk[j] = d >> 8;
    atomicAdd(&hist[bk[j]], 1);
  }
  __syncthreads();
  lbase[t] = atomicAdd(&gcnt[t], hist[t]);   // reserve contiguous chunk per bucket
  __syncthreads();
  #pragma unroll
  for (int j = 0; j < 16; ++j) {
    int e = base + j * 256 + t;
    int pos = atomicAdd(&lbase[bk[j]], 1);
    staging[(size_t)bk[j] * CAPB + pos] = pk[j];
    staging2[(size_t)bk[j] * CAPB + pos] = (unsigned)e;
  }
}

__global__ __launch_bounds__(256) void bucket_pass2(const unsigned* __restrict__ staging,
                                                    const unsigned* __restrict__ staging2,
                                                    const int* __restrict__ gcnt,
                                                    int* __restrict__ row_ptr,
                                                    unsigned short* __restrict__ col,
                                                    unsigned short* __restrict__ dste,
                                                    int* __restrict__ orig) {
  __shared__ int pref[256];
  __shared__ int hist[256];
  __shared__ int loc[256];
  __shared__ int cnt2[256];
  __shared__ unsigned lin[CAPB];
  __shared__ unsigned lout[CAPB];
  __shared__ int lorig[CAPB];
  int t = threadIdx.x, b = blockIdx.x;

  pref[t] = gcnt[t];
  hist[t] = 0;
  __syncthreads();
  for (int off = 1; off < 256; off <<= 1) {      // inclusive scan of bucket counts
    int v = (t >= off) ? pref[t - off] : 0;
    __syncthreads();
    pref[t] += v;
    __syncthreads();
  }
  int rowbase = (b > 0) ? pref[b - 1] : 0;
  int nb = gcnt[b];

  for (int i = t; i < nb; i += 256) {
    unsigned v = staging[(size_t)b * CAPB + i];
    lin[i] = v;
    atomicAdd(&hist[v & 255], 1);
  }
  __syncthreads();
  loc[t] = hist[t];
  __syncthreads();
  for (int off = 1; off < 256; off <<= 1) {      // inclusive scan of local hist
    int v = (t >= off) ? loc[t - off] : 0;
    __syncthreads();
    loc[t] += v;
    __syncthreads();
  }
  int excl = loc[t] - hist[t];
  row_ptr[b * 256 + t] = rowbase + excl;
  cnt2[t] = excl;
  if (b == 255 && t == 255) row_ptr[NN] = rowbase + nb;
  __syncthreads();
  for (int i = t; i < nb; i += 256) {
    unsigned v = lin[i];
    int r = atomicAdd(&cnt2[v & 255], 1);
    lout[r] = v;
    lorig[r] = (int)staging2[(size_t)b * CAPB + i];
  }
  __syncthreads();
  for (int i = t; i < nb; i += 256) {            // coalesced final writes
    unsigned v = lout[i];
    col[rowbase + i] = (unsigned short)(v >> 8);
    dste[rowbase + i] = (unsigned short)(b * 256 + (v & 255));
    orig[rowbase + i] = lorig[i];
  }
}

// -------- dense: h = x@W, al_s/al_d, residual; register-blocked over nodes --------
// writes f32 als/ald for gather + bf16 combo rows (cs: als, cd: ald) for amean.
template<int DIN, int DOUT, int H, bool HAS_RES, int NPW, int CS_OFF, int ALD_OFF>
__global__ __launch_bounds__(256) void gemm_al_kernel(
    const float* __restrict__ xin, const float* __restrict__ W,
    const float* __restrict__ asrc, const float* __restrict__ adst,
    const float* __restrict__ Aw, const float* __restrict__ Ab,
    unsigned short* __restrict__ hw16, float* __restrict__ res,
    float* __restrict__ als, float* __restrict__ ald,
    unsigned short* __restrict__ cs, unsigned short* __restrict__ cd)
{
  constexpr int GPW = 64 / DOUT;
  constexpr int NPB = 4 * NPW * GPW;   // nodes per block (4 waves)
  constexpr int DINP = DIN + 4;        // padded LDS stride
  __shared__ float xs[NPB][DINP];

  int wave = threadIdx.x >> 6;
  int lane = threadIdx.x & 63;
  int l = lane % DOUT;
  int sub = lane / DOUT;
  int block_base = blockIdx.x * NPB;

  {
    constexpr int NV = NPB * DIN / 4;
    const float4* xin4 = (const float4*)(xin + (size_t)block_base * DIN);
    for (int i = threadIdx.x; i < NV; i += 256) {
      float4 v = xin4[i];
      int flat = i * 4;
      int nd = flat / DIN, k = flat % DIN;
      *(float4*)&xs[nd][k] = v;
    }
  }
  __syncthreads();

  int nl = wave * (NPW * GPW) + sub * NPW;
  float acc[NPW], racc[NPW];
  #pragma unroll
  for (int n = 0; n < NPW; ++n) { acc[n] = 0.f; racc[n] = 0.f; }

  for (int k = 0; k < DIN; k += 4) {
    float w0 = W[(k + 0) * DOUT + l];
    float w1 = W[(k + 1) * DOUT + l];
    float w2 = W[(k + 2) * DOUT + l];
    float w3 = W[(k + 3) * DOUT + l];
    float a0 = 0.f, a1 = 0.f, a2 = 0.f, a3 = 0.f;
    if (HAS_RES) {
      a0 = Aw[(k + 0) * DOUT + l];
      a1 = Aw[(k + 1) * DOUT + l];
      a2 = Aw[(k + 2) * DOUT + l];
      a3 = Aw[(k + 3) * DOUT + l];
    }
    #pragma unroll
    for (int n = 0; n < NPW; ++n) {
      float4 xv = *(const float4*)&xs[nl + n][k];
      acc[n] = fmaf(xv.x, w0, fmaf(xv.y, w1, fmaf(xv.z, w2, fmaf(xv.w, w3, acc[n]))));
      if (HAS_RES)
        racc[n] = fmaf(xv.x, a0, fmaf(xv.y, a1, fmaf(xv.z, a2, fmaf(xv.w, a3, racc[n]))));
    }
  }

  int head = l >> 2, c = l & 3;
  float sa = asrc[l];
  float da = adst[l];
  #pragma unroll
  for (int n = 0; n < NPW; ++n) {
    size_t node = (size_t)(block_base + nl + n);
    float hh = acc[n];
    hw16[node * DOUT + l] = f2bf(hh);
    if (HAS_RES) res[node * DOUT + l] = racc[n] + Ab[l];
    float ps = hh * sa, pd = hh * da;
    ps += __shfl_xor(ps, 1); ps += __shfl_xor(ps, 2);
    pd += __shfl_xor(pd, 1); pd += __shfl_xor(pd, 2);
    if (c == 0) {
      als[node * H + head] = ps;
      ald[node * H + head] = pd;
      cs[node * 32 + CS_OFF + head] = f2bf(ps);
      cd[node * 64 + ALD_OFF + head] = f2bf(pd);
    }
  }
}

// ---------------- fused gather: bf16x2 channels, DOUT/2 lanes per node ----------------
template<int DOUT, int H, bool HAS_RES, int INV_OFF>
__global__ __launch_bounds__(256) void gat_gather_kernel(
    const int* __restrict__ row_ptr, const unsigned short* __restrict__ col,
    const float* __restrict__ als, const float* __restrict__ ald,
    const unsigned* __restrict__ hw2,   // bf16x2: channels (2l, 2l+1)
    const float* __restrict__ bias, const float* __restrict__ g,
    const float* __restrict__ be, const float* __restrict__ res,
    float* __restrict__ out, unsigned short* __restrict__ cd)
{
  constexpr int G = DOUT / 2;          // lanes per node
  int tid = blockIdx.x * 256 + threadIdx.x;
  int node = tid / G;
  int l = threadIdx.x % G;             // group lane: channels 2l, 2l+1
  int h = l >> 1;                      // head (2 lanes per head)

  int r0 = row_ptr[node], r1 = row_ptr[node + 1];
  float ald_h = ald[node * H + h];

  float acc0 = 0.f, acc1 = 0.f, ss = 0.f;
  int e = r0;
  for (; e + 3 < r1; e += 4) {
    int s0 = col[e], s1 = col[e + 1], s2 = col[e + 2], s3 = col[e + 3];
    float av0 = als[s0 * H + h];
    float av1 = als[s1 * H + h];
    float av2 = als[s2 * H + h];
    float av3 = als[s3 * H + h];
    unsigned p0 = hw2[s0 * G + l];
    unsigned p1 = hw2[s1 * G + l];
    unsigned p2 = hw2[s2 * G + l];
    unsigned p3 = hw2[s3 * G + l];
    float lg0 = lrelu(av0 + ald_h);
    float lg1 = lrelu(av1 + ald_h);
    float lg2 = lrelu(av2 + ald_h);
    float lg3 = lrelu(av3 + ald_h);
    float e0 = __expf(lg0), e1 = __expf(lg1), e2 = __expf(lg2), e3 = __expf(lg3);
    ss += (e0 + e1) + (e2 + e3);
    acc0 += e0 * bflo(p0) + e1 * bflo(p1) + e2 * bflo(p2) + e3 * bflo(p3);
    acc1 += e0 * bfhi(p0) + e1 * bfhi(p1) + e2 * bfhi(p2) + e3 * bfhi(p3);
  }
  for (; e < r1; ++e) {
    int s0 = col[e];
    float av0 = als[s0 * H + h];
    unsigned p0 = hw2[s0 * G + l];
    float lg0 = lrelu(av0 + ald_h);
    float e0 = __expf(lg0);
    ss += e0;
    acc0 += e0 * bflo(p0);
    acc1 += e0 * bfhi(p0);
  }

  float inv = 1.f / ss;                // identical across the 2 lanes of a head
  if ((l & 1) == 0) cd[node * 64 + INV_OFF + h] = f2bf(inv);

  // epilogue: normalize -> bias -> elu -> layernorm -> (+res), 2 channels/lane
  float2 bb = ((const float2*)bias)[l];
  float v0 = acc0 * inv + bb.x;
  float v1 = acc1 * inv + bb.y;
  v0 = v0 > 0.f ? v0 : expm1f(v0);
  v1 = v1 > 0.f ? v1 : expm1f(v1);
  float sum = v0 + v1;
  #pragma unroll
  for (int o = G / 2; o; o >>= 1) sum += __shfl_xor(sum, o);
  float mu = sum * (1.f / DOUT);
  float d0 = v0 - mu, d1 = v1 - mu;
  float vs = d0 * d0 + d1 * d1;
  #pragma unroll
  for (int o = G / 2; o; o >>= 1) vs += __shfl_xor(vs, o);
  float rstd = rsqrtf(vs * (1.f / DOUT) + 1e-5f);
  float2 gg = ((const float2*)g)[l];
  float2 ee = ((const float2*)be)[l];
  float y0 = d0 * rstd * gg.x + ee.x;
  float y1 = d1 * rstd * gg.y + ee.y;
  if (HAS_RES) {
    float2 rr = ((const float2*)res)[node * G + l];
    y0 += rr.x; y1 += rr.y;
  }
  ((float2*)out)[node * G + l] = make_float2(y0, y1);
}

// ---- all-layer amean in CSR order + fused bucket-pack by original edge id ----
// s-side: one aligned 64B bf16 cs line per edge (4MB table, L2-resident).
// d-side: 128B bf16 cd rows, run-sequential (dst-sorted) -> L1/L2-hot.
// 544 blocks x 512 threads x 4 edges: ~17 waves/CU for latency hiding;
// per-bucket chunk = 8 u64 = 64B (still full-line staging writes).
__global__ __launch_bounds__(512) void amean_pack_kernel(
    const unsigned short* __restrict__ col, const unsigned short* __restrict__ dste,
    const int* __restrict__ orig,
    const unsigned* __restrict__ cs, const unsigned* __restrict__ cd,
    unsigned long long* __restrict__ pstag, int* __restrict__ gcnt2,
    float* __restrict__ ssum)
{
  __shared__ int hist[256];
  __shared__ int lbase[256];
  __shared__ float red[3][8];
  int t = threadIdx.x;
  if (t < 256) hist[t] = 0;
  __syncthreads();
  int base = blockIdx.x * EPP;
  unsigned long long pk[4];
  int bk[4];
  bool va[4];
  float ex1 = 0.f, ex2 = 0.f, ex3 = 0.f;
  #pragma unroll
  for (int j = 0; j < 4; ++j) {
    int i = base + j * 512 + t;
    int c = col[i], d = dste[i], oe = orig[i];
    const uint4* csr = (const uint4*)(cs + (size_t)c * 16);
    const uint4* cdr = (const uint4*)(cd + (size_t)d * 32);
    uint4 S0 = csr[0], S1 = csr[1], S2 = csr[2], S3 = csr[3];
    uint4 A0 = cdr[0], A1 = cdr[1], V0 = cdr[2], V1 = cdr[3];
    uint4 A2 = cdr[4], V2 = cdr[5];
    uint4 AV3 = cdr[6];   // x,y = ald3 ; z,w = inv3
    // layer 1 (H=16)
    float t1 = 0.f;
    {
      unsigned S[8] = {S0.x, S0.y, S0.z, S0.w, S1.x, S1.y, S1.z, S1.w};
      unsigned A[8] = {A0.x, A0.y, A0.z, A0.w, A1.x, A1.y, A1.z, A1.w};
      unsigned V[8] = {V0.x, V0.y, V0.z, V0.w, V1.x, V1.y, V1.z, V1.w};
      #pragma unroll
      for (int q = 0; q < 8; ++q) {
        t1 += __expf(lrelu(bflo(S[q]) + bflo(A[q]))) * bflo(V[q])
            + __expf(lrelu(bfhi(S[q]) + bfhi(A[q]))) * bfhi(V[q]);
      }
      t1 *= (1.f / 16.f);
    }
    // layer 2 (H=8)
    float t2 = 0.f;
    {
      unsigned S[4] = {S2.x, S2.y, S2.z, S2.w};
      unsigned A[4] = {A2.x, A2.y, A2.z, A2.w};
      unsigned V[4] = {V2.x, V2.y, V2.z, V2.w};
      #pragma unroll
      for (int q = 0; q < 4; ++q) {
        t2 += __expf(lrelu(bflo(S[q]) + bflo(A[q]))) * bflo(V[q])
            + __expf(lrelu(bfhi(S[q]) + bfhi(A[q]))) * bfhi(V[q]);
      }
      t2 *= (1.f / 8.f);
    }
    // layer 3 (H=4)
    float t3;
    {
      t3 = (__expf(lrelu(bflo(S3.x) + bflo(AV3.x))) * bflo(AV3.z)
          + __expf(lrelu(bfhi(S3.x) + bfhi(AV3.x))) * bfhi(AV3.z)
          + __expf(lrelu(bflo(S3.y) + bflo(AV3.y))) * bflo(AV3.w)
          + __expf(lrelu(bfhi(S3.y) + bfhi(AV3.y))) * bfhi(AV3.w)) * (1.f / 4.f);
    }
    va[j] = (oe < EE);
    bk[j] = oe >> 12;
    pk[j] = ((unsigned long long)(oe & 4095) << 48) |
            ((unsigned long long)f2bf(t3) << 32) |
            ((unsigned long long)f2bf(t2) << 16) |
            (unsigned long long)f2bf(t1);
    if (va[j]) {
      ex1 += __expf(bfw(f2bf(t1)));
      ex2 += __expf(bfw(f2bf(t2)));
      ex3 += __expf(bfw(f2bf(t3)));
      atomicAdd(&hist[bk[j]], 1);
    }
  }
  __syncthreads();
  if (t < 256) lbase[t] = atomicAdd(&gcnt2[t], hist[t]);
  __syncthreads();
  #pragma unroll
  for (int j = 0; j < 4; ++j) {
    if (va[j]) {
      int pos = atomicAdd(&lbase[bk[j]], 1);
      pstag[(size_t)bk[j] * 4096 + pos] = pk[j];
    }
  }
  #pragma unroll
  for (int o = 32; o; o >>= 1) {
    ex1 += __shfl_xor(ex1, o);
    ex2 += __shfl_xor(ex2, o);
    ex3 += __shfl_xor(ex3, o);
  }
  int w = t >> 6;
  if ((t & 63) == 0) { red[0][w] = ex1; red[1][w] = ex2; red[2][w] = ex3; }
  __syncthreads();
  if (t == 0) {
    float s1 = 0.f, s2 = 0.f, s3 = 0.f;
    #pragma unroll
    for (int q = 0; q < 8; ++q) { s1 += red[0][q]; s2 += red[1][q]; s3 += red[2][q]; }
    atomicAdd(&ssum[0], s1);
    atomicAdd(&ssum[1], s2);
    atomicAdd(&ssum[2], s3);
  }
}

// ---- unpack: LDS unbucket, apply softmax scale, fully coalesced e-output writes ----
__global__ __launch_bounds__(256) void unpack_pass(
    const unsigned long long* __restrict__ pstag, const float* __restrict__ ssum,
    float* __restrict__ oute1, float* __restrict__ oute2, float* __restrict__ oute3)
{
  __shared__ float a1[4096], a2[4096], a3[4096];
  int t = threadIdx.x, b = blockIdx.x;
  float i1 = 1.f / ssum[0], i2 = 1.f / ssum[1], i3 = 1.f / ssum[2];
  for (int k = t; k < 4096; k += 256) {
    unsigned long long v = pstag[(size_t)b * 4096 + k];
    int idx = (int)(v >> 48);
    a1[idx] = __expf(bfw((unsigned)(v & 0xffffu))) * i1;
    a2[idx] = __expf(bfw((unsigned)((v >> 16) & 0xffffu))) * i2;
    a3[idx] = __expf(bfw((unsigned)((v >> 32) & 0xffffu))) * i3;
  }
  __syncthreads();
  size_t base = (size_t)b * 4096;
  for (int k = t; k < 4096; k += 256) {
    oute1[base + k] = a1[k];
    oute2[base + k] = a2[k];
    oute3[base + k] = a3[k];
  }
}

// ---------------- per-layer driver ----------------
template<int DIN, int DOUT, int H, bool HAS_RES, int CS_OFF, int ALD_OFF, int INV_OFF>
static void run_layer(const float* xin, const float* W, const float* as_,
                      const float* ad_, const float* bias, const float* Aw,
                      const float* Ab, const float* g, const float* be,
                      const int* row_ptr, const unsigned short* col,
                      unsigned short* hw16, float* res, float* als, float* ald,
                      unsigned short* cs, unsigned short* cd,
                      float* hout, hipStream_t stream)
{
  constexpr int NPW = 8;
  constexpr int NPB = 4 * NPW * (64 / DOUT);
  constexpr int G = DOUT / 2;
  gemm_al_kernel<DIN, DOUT, H, HAS_RES, NPW, CS_OFF, ALD_OFF><<<NN / NPB, 256, 0, stream>>>(
      xin, W, as_, ad_, Aw, Ab, hw16, res, als, ald, cs, cd);
  gat_gather_kernel<DOUT, H, HAS_RES, INV_OFF><<<(NN * G) / 256, 256, 0, stream>>>(
      row_ptr, col, als, ald, (const unsigned*)hw16, bias, g, be, res, hout, cd);
}

extern "C" void kernel_launch(void* const* d_in, const int* in_sizes, int n_in,
                              void* d_out, int out_size, void* d_ws, size_t ws_size,
                              hipStream_t stream)
{
  const float* x   = (const float*)d_in[0];
  const int*   ei  = (const int*)d_in[1];
  const float* W1  = (const float*)d_in[3];
  const float* as1 = (const float*)d_in[4];
  const float* ad1 = (const float*)d_in[5];
  const float* b1  = (const float*)d_in[6];
  const float* W2  = (const float*)d_in[7];
  const float* as2 = (const float*)d_in[8];
  const float* ad2 = (const float*)d_in[9];
  const float* b2  = (const float*)d_in[10];
  const float* W3  = (const float*)d_in[11];
  const float* as3 = (const float*)d_in[12];
  const float* ad3 = (const float*)d_in[13];
  const float* b3  = (const float*)d_in[14];
  const float* A1w = (const float*)d_in[15];
  const float* A1b = (const float*)d_in[16];
  const float* A2w = (const float*)d_in[17];
  const float* A2b = (const float*)d_in[18];
  const float* g1  = (const float*)d_in[19];
  const float* be1 = (const float*)d_in[20];
  const float* g2  = (const float*)d_in[21];
  const float* be2 = (const float*)d_in[22];
  const float* g3  = (const float*)d_in[23];
  const float* be3 = (const float*)d_in[24];

  float* ws = (float*)d_ws;
  size_t off = 0;
  float* h1       = ws + off; off += (size_t)NN * 64;
  float* h2       = ws + off; off += (size_t)NN * 32;
  unsigned short* hw16 = (unsigned short*)(ws + off); off += (size_t)NN * 32;
  float* res      = ws + off; off += (size_t)NN * 64;
  float* als      = ws + off; off += (size_t)NN * 16;
  float* ald      = ws + off; off += (size_t)NN * 16;
  unsigned short* cs = (unsigned short*)(ws + off); off += (size_t)NN * 16;  // 32 bf16/node
  unsigned short* cd = (unsigned short*)(ws + off); off += (size_t)NN * 32;  // 64 bf16/node
  float* scal     = ws + off; off += 16;
  int* row_ptr    = (int*)(ws + off); off += NN + 4;
  unsigned short* col  = (unsigned short*)(ws + off); off += (size_t)ET / 2 + 4;
  unsigned short* dste = (unsigned short*)(ws + off); off += (size_t)ET / 2 + 4;
  int* orig       = (int*)(ws + off); off += ET;
  int* gcnt       = (int*)(ws + off); off += 256;
  int* gcnt2      = (int*)(ws + off); off += 256;
  unsigned* staging  = (unsigned*)(ws + off); off += (size_t)256 * CAPB;
  unsigned* staging2 = (unsigned*)(ws + off); off += (size_t)256 * CAPB;
  if (off & 1) off++;  // 8B align
  unsigned long long* pstag = (unsigned long long*)(ws + off); off += (size_t)EE * 2;

  float* outh3 = (float*)d_out;
  float* oute1 = outh3 + (size_t)NN * 16;
  float* oute2 = oute1 + EE;
  float* oute3 = oute2 + EE;

  // ---- CSR build via coarse-bucket sort (graph-capture safe) ----
  hipMemsetAsync(gcnt, 0, 512 * sizeof(int), stream);   // gcnt + gcnt2 (adjacent)
  hipMemsetAsync(scal, 0, 16, stream);
  bucket_pass1<<<P1B, 256, 0, stream>>>(ei, staging, staging2, gcnt);
  bucket_pass2<<<256, 256, 0, stream>>>(staging, staging2, gcnt, row_ptr, col, dste, orig);

  // combo layout (bf16 units): cs row 32/node: L1@0 L2@16 L3@24
  // cd row 64/node: ald1@0 inv1@16 ald2@32 inv2@40 ald3@48 inv3@52
  run_layer<84, 64, 16, true, 0, 0, 16>(x, W1, as1, ad1, b1, A1w, A1b, g1, be1,
                                        row_ptr, col, hw16, res, als, ald,
                                        cs, cd, h1, stream);
  run_layer<64, 32, 8, true, 16, 32, 40>(h1, W2, as2, ad2, b2, A2w, A2b, g2, be2,
                                         row_ptr, col, hw16, res, als, ald,
                                         cs, cd, h2, stream);
  run_layer<32, 16, 4, false, 24, 48, 52>(h2, W3, as3, ad3, b3, nullptr, nullptr, g3, be3,
                                          row_ptr, col, hw16, res, als, ald,
                                          cs, cd, outh3, stream);

  amean_pack_kernel<<<ET / EPP, 512, 0, stream>>>(
      col, dste, orig, (const unsigned*)cs, (const unsigned*)cd, pstag, gcnt2, scal);
  unpack_pass<<<256, 256, 0, stream>>>(pstag, scal, oute1, oute2, oute3);
}